// Round 10
// baseline (288.255 us; speedup 1.0000x reference)
//
#include <hip/hip_runtime.h>

#define NUSERS 100000
#define NBOOKS 50000
#define HID 128
#define FEAT 256
#define EPR 500000
#define NEDGE (2 * EPR)

#define UBLK64 ((NUSERS + 63) / 64)         // 1563
#define BBLK64 ((NBOOKS + 63) / 64)         // 782
#define GH_BLOCKS (UBLK64 + BBLK64)         // 2345 (x512 edges >= NEDGE)
#define FILL_B ((NEDGE + 255) / 256)        // 3907
#define NXCD 8

typedef __attribute__((ext_vector_type(8))) short bf16x8;
typedef __attribute__((ext_vector_type(4))) float f32x4;

__device__ __forceinline__ unsigned short f2bf(float f) {
  union { float f; unsigned u; } v; v.f = f;
  unsigned r = v.u + 0x7FFFu + ((v.u >> 16) & 1u);   // RNE
  return (unsigned short)(r >> 16);
}
__device__ __forceinline__ float bf2f(unsigned short h) {
  union { unsigned u; float f; } v; v.u = ((unsigned)h) << 16;
  return v.f;
}
__device__ __forceinline__ unsigned pk2bf(float lo, float hi) {
  unsigned r;
  asm("v_cvt_pk_bf16_f32 %0, %1, %2" : "=v"(r) : "v"(lo), "v"(hi));
  return r;
}
__device__ __forceinline__ int xcc_id() {
  unsigned id;
  asm volatile("s_getreg_b32 %0, hwreg(HW_REG_XCC_ID)" : "=s"(id));
  return (int)(id & 7);
}

// ---------------------------------------------------------------------------
__global__ void cast_w(const float* __restrict__ w0, const float* __restrict__ w1,
                       unsigned short* __restrict__ o0, unsigned short* __restrict__ o1)
{
  int i = blockIdx.x * 256 + threadIdx.x;
  if (i < HID * FEAT) { o0[i] = f2bf(w0[i]); o1[i] = f2bf(w1[i]); }
}

// ---------------------------------------------------------------------------
__device__ __forceinline__ void decode_edge(const int* __restrict__ rates,
                                            const int* __restrict__ impl,
                                            int i, int& u, int& bk)
{
  if (i < EPR) { u = rates[i]; bk = rates[EPR + i]; }
  else { int j = i - EPR; u = impl[j]; bk = impl[EPR + j]; }
}

// ---------------------------------------------------------------------------
// Fused barrier-free GEMM + XCD-LOCAL histogram (R9 design, unsigned-decode
// fix). 8 per-XCD copies of cntb/degu; workgroup-scope atomics execute in the
// local XCD L2. Each copy is only touched by waves physically on that XCD
// (XCC_ID hwreg), so L2-local atomicity is sufficient; cross-kernel
// visibility comes from the end-of-dispatch release (per-XCD L2 writeback).
// relpos packs (xcd<<29)|slot, handled as UNSIGNED end-to-end.
// Atomics issue FIRST: ~200cy L2 latency drains under the ~900cy HBM staging
// wait. GEMM: R8's verified structure (wave-private 16-row tiles, two
// K-halves, wave-local vmcnt waits, 0-conflict XOR LDS layout).
// ---------------------------------------------------------------------------
__global__ __launch_bounds__(256) void gemm_hist(
    const float* __restrict__ Xu, const float* __restrict__ Xb,
    const unsigned short* __restrict__ Wu, const unsigned short* __restrict__ Wb,
    const float* __restrict__ bu, const float* __restrict__ bb,
    unsigned short* __restrict__ cu0b, float* __restrict__ outb,
    float* __restrict__ outu,
    const int* __restrict__ rates, const int* __restrict__ impl,
    int* __restrict__ degu8, int* __restrict__ cntb8,
    unsigned* __restrict__ relpos)
{
  __shared__ float Asb[4][2048];   // 4 waves x 8 KB = 32 KB
  const int bid = blockIdx.x;
  const int tid = threadIdx.x;
  const int lane = tid & 63;
  const int wv   = tid >> 6;
  const int l15  = lane & 15, l4 = lane >> 4;

  // ---- histogram first: L2-local atomics drain under the staging wait ----
  {
    const unsigned x = (unsigned)xcc_id();
    int* cnt = cntb8 + (size_t)x * NBOOKS;
    int* deg = degu8 + (size_t)x * NUSERS;
    const int e0 = bid * 512 + tid;
#pragma unroll
    for (int q = 0; q < 2; ++q) {
      int e = e0 + q * 256;
      if (e < NEDGE) {
        int u, bk;
        decode_edge(rates, impl, e, u, bk);
        unsigned p = (unsigned)__hip_atomic_fetch_add(&cnt[bk], 1, __ATOMIC_RELAXED,
                                                      __HIP_MEMORY_SCOPE_WORKGROUP);
        __hip_atomic_fetch_add(&deg[u], 1, __ATOMIC_RELAXED,
                               __HIP_MEMORY_SCOPE_WORKGROUP);
        relpos[e] = (x << 29) | (p & 0x1FFFFFFFu);
      }
    }
  }

  // ---- GEMM ----
  const bool isU = bid < UBLK64;
  const float* __restrict__ X = isU ? Xu : Xb;
  const unsigned short* __restrict__ W = isU ? Wu : Wb;
  const float* __restrict__ bias = isU ? bu : bb;
  const int M    = isU ? NUSERS : NBOOKS;
  const int bm   = (isU ? bid : bid - UBLK64) * 64;
  const int wrow = bm + wv * 16;

  float* wbase = &Asb[wv][0];

  f32x4 acc[8];
#pragma unroll
  for (int ni = 0; ni < 8; ++ni) acc[ni] = (f32x4)0.f;

#pragma unroll
  for (int h = 0; h < 2; ++h) {
    if (h) {
      asm volatile("s_waitcnt lgkmcnt(0)" ::: "memory");
      __builtin_amdgcn_sched_barrier(0);
    }
#pragma unroll
    for (int rnd = 0; rnd < 8; ++rnd) {
      int o = rnd * 64 + lane;
      int r = o >> 5;                 // 0..15
      int c = o & 31;                 // phys 16B-unit within row
      int lc = c ^ r;                 // logical unit (inverse swizzle on src)
      int gr = wrow + r; if (gr > M - 1) gr = M - 1;
      __builtin_amdgcn_global_load_lds(
          (const float*)&X[(size_t)gr * FEAT + h * 128 + lc * 4],
          wbase + rnd * 256, 16, 0, 0);
    }
    asm volatile("s_waitcnt vmcnt(0)" ::: "memory");
    __builtin_amdgcn_sched_barrier(0);

#pragma unroll
    for (int ks = 0; ks < 4; ++ks) {
      const int kg = h * 4 + ks;
      bf16x8 bfr[8];
#pragma unroll
      for (int ni = 0; ni < 8; ++ni)
        bfr[ni] = *reinterpret_cast<const bf16x8*>(
            &W[(size_t)(ni * 16 + l15) * FEAT + kg * 32 + l4 * 8]);

      int u0 = (ks * 8 + l4 * 2) ^ l15;
      int u1 = (ks * 8 + l4 * 2 + 1) ^ l15;
      f32x4 a0 = *reinterpret_cast<const f32x4*>(&wbase[(l15 * 32 + u0) * 4]);
      f32x4 a1 = *reinterpret_cast<const f32x4*>(&wbase[(l15 * 32 + u1) * 4]);
      union { unsigned u32[4]; bf16x8 v; } au;
      au.u32[0] = pk2bf(a0[0], a0[1]);
      au.u32[1] = pk2bf(a0[2], a0[3]);
      au.u32[2] = pk2bf(a1[0], a1[1]);
      au.u32[3] = pk2bf(a1[2], a1[3]);

#pragma unroll
      for (int ni = 0; ni < 8; ++ni)
        acc[ni] = __builtin_amdgcn_mfma_f32_16x16x32_bf16(au.v, bfr[ni], acc[ni], 0, 0, 0);
    }
  }

  // ---- C epilogue ----
#pragma unroll
  for (int ni = 0; ni < 8; ++ni) {
    int col = ni * 16 + l15;
    float bj = bias[col];
#pragma unroll
    for (int j = 0; j < 4; ++j) {
      int rr = wrow + l4 * 4 + j;
      if (rr < M) {
        float vv = acc[ni][j] + bj;
        if (isU) {
          cu0b[(size_t)rr * HID + col] = f2bf(vv);
          if (rr >= NBOOKS) outu[(size_t)rr * HID + col] = vv * (1.0f / 3.0f);
        } else {
          outb[(size_t)rr * HID + col] = vv * (1.0f / 3.0f);
        }
      }
    }
  }
}

// ---------------------------------------------------------------------------
// Merge the 8 per-XCD histograms: cntb8[x][i] overwritten IN PLACE with the
// per-bin exclusive base; cntb[i] = bin total; dis[i] = rsqrt(total degree).
// ---------------------------------------------------------------------------
__global__ void merge_dis(int* __restrict__ cntb8, const int* __restrict__ degu8,
                          int* __restrict__ cntb, float* __restrict__ dis)
{
  int i = blockIdx.x * 256 + threadIdx.x;
  if (i >= NUSERS) return;
  int d = 0;
#pragma unroll
  for (int x = 0; x < NXCD; ++x) d += degu8[(size_t)x * NUSERS + i];
  if (i < NBOOKS) {
    int run = 0;
#pragma unroll
    for (int x = 0; x < NXCD; ++x) {
      int c = cntb8[(size_t)x * NBOOKS + i];
      cntb8[(size_t)x * NBOOKS + i] = run;
      run += c;
    }
    cntb[i] = run;
    d += run;
  }
  dis[i] = (d > 0) ? rsqrtf((float)d) : 0.f;
}

// ---------------------------------------------------------------------------
__global__ void fill_scatter(const int* __restrict__ rates, const int* __restrict__ impl,
                             const int* __restrict__ offs,
                             const unsigned* __restrict__ relpos,
                             const int* __restrict__ cntb8,
                             int* __restrict__ brow)
{
  int i = blockIdx.x * 256 + threadIdx.x;
  if (i >= NEDGE) return;
  int u, bk;
  decode_edge(rates, impl, i, u, bk);
  unsigned rp = relpos[i];
  unsigned x  = (rp >> 29) & 7u;               // LOGICAL shift (unsigned)
  int rel     = (int)(rp & 0x1FFFFFFFu);
  brow[offs[bk] + cntb8[(size_t)x * NBOOKS + bk] + rel] = u;
}

// ---------------------------------------------------------------------------
__global__ __launch_bounds__(1024) void scan_blocks(const int* __restrict__ counts,
                                                    int* __restrict__ offs,
                                                    int* __restrict__ bsum, int N)
{
  __shared__ int buf[1024];
  int t = threadIdx.x;
  int i = blockIdx.x * 1024 + t;
  int v = (i < N) ? counts[i] : 0;
  buf[t] = v;
  __syncthreads();
  for (int off = 1; off < 1024; off <<= 1) {
    int x = (t >= off) ? buf[t - off] : 0;
    __syncthreads();
    buf[t] += x;
    __syncthreads();
  }
  int incl = buf[t];
  if (i < N) offs[i] = incl - v;
  if (t == 1023) bsum[blockIdx.x] = incl;
}

__global__ void scan_totals(const int* __restrict__ bsum, int* __restrict__ bpre,
                            int* __restrict__ offs, int nb, int N)
{
  if (threadIdx.x == 0 && blockIdx.x == 0) {
    int run = 0;
    for (int b = 0; b < nb; ++b) { bpre[b] = run; run += bsum[b]; }
    offs[N] = run;
  }
}

__global__ void add_prefix(int* __restrict__ offs, const int* __restrict__ bpre, int N)
{
  int i = blockIdx.x * blockDim.x + threadIdx.x;
  if (i < N) offs[i] += bpre[i >> 10];
}

// ---------------------------------------------------------------------------
// Pull layer 1: wave per dest, 4 lane-groups of 16, 8 rows in flight.
// ---------------------------------------------------------------------------
__global__ __launch_bounds__(256) void pull1(const unsigned short* __restrict__ srcb,
    const int* __restrict__ offs, const int* __restrict__ brow,
    const float* __restrict__ dis, unsigned short* __restrict__ dstb)
{
  int c = (blockIdx.x << 2) + (threadIdx.x >> 6);
  if (c >= NBOOKS) return;
  const int lane = threadIdx.x & 63;
  const int g = lane >> 4, l = lane & 15;
  const int s = offs[c], e = offs[c + 1];

  float acc[8];
#pragma unroll
  for (int j = 0; j < 8; ++j) acc[j] = 0.f;

  int i = s + g;
  for (; i + 4 < e; i += 8) {
    int rr0 = brow[i], rr1 = brow[i + 4];
    float w0 = dis[rr0], w1 = dis[rr1];
    bf16x8 v0 = *reinterpret_cast<const bf16x8*>(&srcb[(size_t)rr0 * HID + l * 8]);
    bf16x8 v1 = *reinterpret_cast<const bf16x8*>(&srcb[(size_t)rr1 * HID + l * 8]);
#pragma unroll
    for (int j = 0; j < 8; ++j) acc[j] += w0 * bf2f((unsigned short)v0[j]);
#pragma unroll
    for (int j = 0; j < 8; ++j) acc[j] += w1 * bf2f((unsigned short)v1[j]);
  }
  if (i < e) {
    int rr = brow[i];
    float w = dis[rr];
    bf16x8 v = *reinterpret_cast<const bf16x8*>(&srcb[(size_t)rr * HID + l * 8]);
#pragma unroll
    for (int j = 0; j < 8; ++j) acc[j] += w * bf2f((unsigned short)v[j]);
  }

#pragma unroll
  for (int j = 0; j < 8; ++j) {
    acc[j] += __shfl_xor(acc[j], 16, 64);
    acc[j] += __shfl_xor(acc[j], 32, 64);
  }
  if (g == 0) {
    float db = dis[c];
    bf16x8 o;
#pragma unroll
    for (int j = 0; j < 8; ++j) o[j] = (short)f2bf(db * acc[j]);
    *reinterpret_cast<bf16x8*>(&dstb[(size_t)c * HID + l * 8]) = o;
  }
}

// Layer 2 + final mean (dests < NBOOKS). Branchless clamped gathers of h1b.
__global__ __launch_bounds__(256) void pull2_final(const unsigned short* __restrict__ h1b,
    const int* __restrict__ offs, const int* __restrict__ brow,
    const float* __restrict__ dis, const unsigned short* __restrict__ cu0b,
    float* __restrict__ outu)
{
  int c = (blockIdx.x << 2) + (threadIdx.x >> 6);
  if (c >= NBOOKS) return;
  const int lane = threadIdx.x & 63;
  const int g = lane >> 4, l = lane & 15;
  const int s = offs[c], e = offs[c + 1];

  float acc[8];
#pragma unroll
  for (int j = 0; j < 8; ++j) acc[j] = 0.f;

  int i = s + g;
  for (; i + 4 < e; i += 8) {
    int rr0 = brow[i], rr1 = brow[i + 4];
    int rc0 = rr0 < NBOOKS ? rr0 : 0;
    int rc1 = rr1 < NBOOKS ? rr1 : 0;
    float w0 = rr0 < NBOOKS ? dis[rr0] : 0.f;
    float w1 = rr1 < NBOOKS ? dis[rr1] : 0.f;
    bf16x8 v0 = *reinterpret_cast<const bf16x8*>(&h1b[(size_t)rc0 * HID + l * 8]);
    bf16x8 v1 = *reinterpret_cast<const bf16x8*>(&h1b[(size_t)rc1 * HID + l * 8]);
#pragma unroll
    for (int j = 0; j < 8; ++j) acc[j] += w0 * bf2f((unsigned short)v0[j]);
#pragma unroll
    for (int j = 0; j < 8; ++j) acc[j] += w1 * bf2f((unsigned short)v1[j]);
  }
  if (i < e) {
    int rr = brow[i];
    int rc = rr < NBOOKS ? rr : 0;
    float w = rr < NBOOKS ? dis[rr] : 0.f;
    bf16x8 v = *reinterpret_cast<const bf16x8*>(&h1b[(size_t)rc * HID + l * 8]);
#pragma unroll
    for (int j = 0; j < 8; ++j) acc[j] += w * bf2f((unsigned short)v[j]);
  }

#pragma unroll
  for (int j = 0; j < 8; ++j) {
    acc[j] += __shfl_xor(acc[j], 16, 64);
    acc[j] += __shfl_xor(acc[j], 32, 64);
  }
  if (g == 0) {
    float db = dis[c];
    size_t idx = (size_t)c * HID + l * 8;
    bf16x8 c0 = *reinterpret_cast<const bf16x8*>(&cu0b[idx]);
    bf16x8 h1 = *reinterpret_cast<const bf16x8*>(&h1b[idx]);
    float r[8];
#pragma unroll
    for (int j = 0; j < 8; ++j)
      r[j] = (bf2f((unsigned short)c0[j]) + bf2f((unsigned short)h1[j]) + db * acc[j]) * (1.0f / 3.0f);
    *reinterpret_cast<float4*>(&outu[idx])     = make_float4(r[0], r[1], r[2], r[3]);
    *reinterpret_cast<float4*>(&outu[idx + 4]) = make_float4(r[4], r[5], r[6], r[7]);
  }
}

// ---------------------------------------------------------------------------
extern "C" void kernel_launch(void* const* d_in, const int* in_sizes, int n_in,
                              void* d_out, int out_size, void* d_ws, size_t ws_size,
                              hipStream_t stream)
{
  const float* user_x = (const float*)d_in[0];
  const float* book_x = (const float*)d_in[1];
  const float* user_W = (const float*)d_in[2];
  const float* user_b = (const float*)d_in[3];
  const float* book_W = (const float*)d_in[4];
  const float* book_b = (const float*)d_in[5];
  const int*   rates  = (const int*)d_in[6];
  const int*   impl   = (const int*)d_in[7];

  float* out      = (float*)d_out;
  float* out_user = out;
  float* out_book = out + (size_t)NUSERS * HID;

  char* p = (char*)d_ws;
  auto carve = [&](size_t bytes) -> void* {
    void* r = (void*)p;
    p += (bytes + 255) & ~(size_t)255;
    return r;
  };
  unsigned short* cu0b   = (unsigned short*)carve((size_t)NUSERS * HID * 2);
  unsigned short* h1b    = (unsigned short*)carve((size_t)NBOOKS * HID * 2);
  unsigned short* wub    = (unsigned short*)carve((size_t)HID * FEAT * 2);
  unsigned short* wbb    = (unsigned short*)carve((size_t)HID * FEAT * 2);
  int*      degu8  = (int*)carve((size_t)NXCD * NUSERS * 4);
  int*      cntb8  = (int*)carve((size_t)NXCD * NBOOKS * 4);
  int*      cntb   = (int*)carve((size_t)NBOOKS * 4);
  float*    dis    = (float*)carve((size_t)NUSERS * 4);
  int*      offs   = (int*)carve((size_t)(NBOOKS + 2) * 4);
  int*      bsum   = (int*)carve(256 * 4);
  int*      bpre   = (int*)carve(256 * 4);
  unsigned* relpos = (unsigned*)carve((size_t)NEDGE * 4);
  int*      brow   = (int*)carve((size_t)NEDGE * 4);

  hipMemsetAsync(degu8, 0, (size_t)NXCD * NUSERS * 4, stream);
  hipMemsetAsync(cntb8, 0, (size_t)NXCD * NBOOKS * 4, stream);

  cast_w<<<(HID * FEAT + 255) / 256, 256, 0, stream>>>(user_W, book_W, wub, wbb);

  // fused GEMM + XCD-local histogram
  gemm_hist<<<GH_BLOCKS, 256, 0, stream>>>(
      user_x, book_x, wub, wbb, user_b, book_b,
      cu0b, out_book, out_user, rates, impl, degu8, cntb8, relpos);

  // merge per-XCD histograms -> totals, per-XCD bases (in place), dis
  merge_dis<<<(NUSERS + 255) / 256, 256, 0, stream>>>(cntb8, degu8, cntb, dis);

  const int nb = (NBOOKS + 1023) / 1024;
  scan_blocks<<<nb, 1024, 0, stream>>>(cntb, offs, bsum, NBOOKS);
  scan_totals<<<1, 64, 0, stream>>>(bsum, bpre, offs, nb, NBOOKS);
  add_prefix<<<(NBOOKS + 255) / 256, 256, 0, stream>>>(offs, bpre, NBOOKS);

  // CSR fill (atomic-free scatter)
  fill_scatter<<<FILL_B, 256, 0, stream>>>(rates, impl, offs, relpos, cntb8, brow);

  // propagation (dests < NBOOKS), layer 2 fuses final mean
  pull1<<<(NBOOKS + 3) / 4, 256, 0, stream>>>(cu0b, offs, brow, dis, h1b);
  pull2_final<<<(NBOOKS + 3) / 4, 256, 0, stream>>>(h1b, offs, brow, dis, cu0b, out_user);
}